// Round 16
// baseline (1655.007 us; speedup 1.0000x reference)
//
#include <hip/hip_runtime.h>
#include <cmath>

#define BN 2048
#define TN 512
#define HN 256
#define ROWS 8
#define WAVES 8
#define THREADS 512
#define NBLK (BN / ROWS)   // 256 blocks = 1 per CU
#define HP (HN + 8)        // padded h row: 528 B (32 data blocks + pad)

// h-tile swizzle: 16B block m of row r stored at block ((m - 2r) & 31).
// A-read (row=li) bank-quad becomes (m - li) mod 8 -> bijective in li -> 2-way.
#define HSWZ(m, r) ((((m) - 2 * (r)) & 31))

typedef _Float16 half_t;
typedef _Float16 f16x8 __attribute__((ext_vector_type(8)));
typedef _Float16 f16x4 __attribute__((ext_vector_type(4)));
typedef float f32x4 __attribute__((ext_vector_type(4)));
typedef unsigned uint2v __attribute__((ext_vector_type(2)));

__device__ __forceinline__ float sigf(float v) {
    return __builtin_amdgcn_rcpf(1.0f + __expf(-v));
}
__device__ __forceinline__ float tanhf_fast(float v) {
    return 1.0f - 2.0f * __builtin_amdgcn_rcpf(1.0f + __expf(2.0f * v));
}

// fold u0/u1 across lane halves (R15-proven builtin; shfl fallback)
__device__ __forceinline__ float fold_half(float a0, float a1, int lane) {
#if __has_builtin(__builtin_amdgcn_permlane32_swap)
    uint2v res = __builtin_amdgcn_permlane32_swap(
        __builtin_bit_cast(unsigned, a0), __builtin_bit_cast(unsigned, a1),
        false, false);
    return __builtin_bit_cast(float, res[0]);
#else
    float v0 = (lane < 32) ? a0 : 0.f;
    float sw = __shfl_xor(a1, 32, 64);
    return (lane >= 32) ? sw : v0;
#endif
}

// Pack W_hh [4H][H] fp32 -> fp16 fragment stream (UNSCALED — R5 numerics).
// idx bits: e[0:3) lane[3:9) kc[9:12) nt[12:15) w[15:18)
//   nt = u*4 + g; n = g*256 + 32*w + u*16 + (lane&15); k = kc*32+(lane>>4)*8+e
__global__ void pack_w(const float* __restrict__ Whh, half_t* __restrict__ W4) {
    int idx = blockIdx.x * 256 + threadIdx.x;
    if (idx >= 4 * HN * HN) return;
    int e = idx & 7;
    int lane = (idx >> 3) & 63;
    int kc = (idx >> 9) & 7;
    int nt = (idx >> 12) & 7;
    int w = (idx >> 15) & 7;
    int g = nt & 3, u = nt >> 2;
    int n = g * HN + 32 * w + u * 16 + (lane & 15);
    int k = kc * 32 + (lane >> 4) * 8 + e;
    W4[idx] = (half_t)Whh[(size_t)n * HN + k];
}

__device__ __forceinline__ f16x8 raw_frag(const float* __restrict__ Whh, int w,
                                          int g, int u, int kc, int li, int lh) {
    int n = g * HN + 32 * w + u * 16 + li;
    const float* p = Whh + (size_t)n * HN + kc * 32 + lh * 8;
    float4 lo = *reinterpret_cast<const float4*>(p);
    float4 hi = *reinterpret_cast<const float4*>(p + 4);
    f16x8 v;
    v[0] = (half_t)lo.x; v[1] = (half_t)lo.y;
    v[2] = (half_t)lo.z; v[3] = (half_t)lo.w;
    v[4] = (half_t)hi.x; v[5] = (half_t)hi.y;
    v[6] = (half_t)hi.z; v[7] = (half_t)hi.w;
    return v;
}

template <bool PACKED>
__global__ __launch_bounds__(THREADS, 2) void lstm_hot(
    const float* __restrict__ x,      // [B][T]
    const float* __restrict__ W_ih,   // [4H]
    const half_t* __restrict__ W4,    // packed fragments (PACKED)
    const float* __restrict__ Whh,    // raw fallback
    const float* __restrict__ b_ih, const float* __restrict__ b_hh,
    const float* __restrict__ W_lin, const float* __restrict__ b_lin,
    float* __restrict__ out)          // [B][T]
{
    __shared__ __align__(16) half_t ldsW[WAVES][2][8][512];  // 128 KB (gate-3)
    __shared__ __align__(16) half_t h_lds[2][16][HP];        // 16.5 KB dbuf
    __shared__ float2 bw_lds[4 * HN];                        // 8 KB {bias, w_ih}
    __shared__ float wl_lds[HN];                             // 1 KB

    const int tid = threadIdx.x;
    const int lane = tid & 63;
    const int w = tid >> 6;        // wave w: units 32w..32w+31, out row w
    const int li = lane & 15;
    const int lh = lane >> 4;      // 0..3
    const int brow0 = blockIdx.x * ROWS;

    for (int i = tid; i < 4 * HN; i += THREADS)
        bw_lds[i] = make_float2(b_ih[i] + b_hh[i], W_ih[i]);
    for (int i = tid; i < HN; i += THREADS) wl_lds[i] = W_lin[i];
    for (int i = tid; i < 2 * 16 * HP; i += THREADS)
        (&h_lds[0][0][0])[i] = (half_t)0.0f;   // zeros: swizzle-invariant

    // ---- weights: gates 0..2 in registers/AGPRs (192), gate 3 in LDS ----
    f16x8 Wv[3][2][8];
    if (PACKED) {
        const half_t* Wb = W4 + ((size_t)w << 15) + lane * 8;
#pragma unroll
        for (int g = 0; g < 3; ++g)
#pragma unroll
            for (int u = 0; u < 2; ++u)
#pragma unroll
                for (int kc = 0; kc < 8; ++kc)
                    Wv[g][u][kc] = *reinterpret_cast<const f16x8*>(
                        Wb + (((u * 4 + g) << 12) | (kc << 9)));
#pragma unroll
        for (int u = 0; u < 2; ++u)
#pragma unroll
            for (int kc = 0; kc < 8; ++kc)
                *reinterpret_cast<f16x8*>(&ldsW[w][u][kc][lane * 8]) =
                    *reinterpret_cast<const f16x8*>(
                        Wb + (((u * 4 + 3) << 12) | (kc << 9)));
    } else {
#pragma unroll
        for (int g = 0; g < 3; ++g)
#pragma unroll
            for (int u = 0; u < 2; ++u)
#pragma unroll
                for (int kc = 0; kc < 8; ++kc)
                    Wv[g][u][kc] = raw_frag(Whh, w, g, u, kc, li, lh);
#pragma unroll
        for (int u = 0; u < 2; ++u)
#pragma unroll
            for (int kc = 0; kc < 8; ++kc)
                *reinterpret_cast<f16x8*>(&ldsW[w][u][kc][lane * 8]) =
                    raw_frag(Whh, w, 3, u, kc, li, lh);
    }

    const int unit = 32 * w + (lane >= 32 ? 16 : 0) + li;
    const int xbase = (lh & 1) * 4;  // rows xbase..xbase+3
    const float* xptr = x + (size_t)(brow0 + xbase) * TN;

    float c[4] = {0.0f, 0.0f, 0.0f, 0.0f};
    const float blin = b_lin[0];
    float ov = 0.0f;  // out[w][·]: lane s holds out value for step (blk*64+s)

    // h-write swizzled column base: unit's 16B-block is unit>>3, offset unit&7
    const int wr_mu = unit >> 3;
    const int wr_e = unit & 7;

    __syncthreads();

    // hoist loop-invariant bias/w_ih into registers (verified via R11 pass)
    float2 bw[4];
#pragma unroll
    for (int g = 0; g < 4; ++g) bw[g] = bw_lds[g * HN + unit];

    for (int t = 0; t < TN; ++t) {
        const int p = t & 1;  // buffer holding h_{t-1}

        // x for this step (issued early; L1-resident after first sweep)
        float xr[4];
#pragma unroll
        for (int r = 0; r < 4; ++r) xr[r] = xptr[(size_t)r * TN + t];

        // gates: 8 independent MFMA chains, A loaded once per kc.
        // A-read row li, k-block m = kc*4+lh, swizzled -> 2-way (free) banks.
        f32x4 acc[4][2];
#pragma unroll
        for (int g = 0; g < 4; ++g)
#pragma unroll
            for (int u = 0; u < 2; ++u)
                acc[g][u] = f32x4{0.f, 0.f, 0.f, 0.f};

        __builtin_amdgcn_s_setprio(1);
#pragma unroll
        for (int kc = 0; kc < 8; ++kc) {
            f16x8 a = *reinterpret_cast<const f16x8*>(
                &h_lds[p][li][HSWZ(kc * 4 + lh, li) * 8]);
            f16x8 b3u0 = *reinterpret_cast<const f16x8*>(&ldsW[w][0][kc][lane * 8]);
            f16x8 b3u1 = *reinterpret_cast<const f16x8*>(&ldsW[w][1][kc][lane * 8]);
#pragma unroll
            for (int g = 0; g < 3; ++g) {
                acc[g][0] = __builtin_amdgcn_mfma_f32_16x16x32_f16(
                    a, Wv[g][0][kc], acc[g][0], 0, 0, 0);
                acc[g][1] = __builtin_amdgcn_mfma_f32_16x16x32_f16(
                    a, Wv[g][1][kc], acc[g][1], 0, 0, 0);
            }
            acc[3][0] = __builtin_amdgcn_mfma_f32_16x16x32_f16(a, b3u0, acc[3][0], 0, 0, 0);
            acc[3][1] = __builtin_amdgcn_mfma_f32_16x16x32_f16(a, b3u1, acc[3][1], 0, 0, 0);
        }
        __builtin_amdgcn_s_setprio(0);

        // fold u0/u1 across lane halves (builtin permlane32_swap; R15-proven)
        float fold[4][4];
#pragma unroll
        for (int g = 0; g < 4; ++g)
#pragma unroll
            for (int r = 0; r < 4; ++r)
                fold[g][r] = fold_half(acc[g][0][r], acc[g][1][r], lane);

        float hnew[4];
#pragma unroll
        for (int r = 0; r < 4; ++r) {
            float gi = sigf(fold[0][r] + bw[0].x + xr[r] * bw[0].y);
            float gf = sigf(fold[1][r] + bw[1].x + xr[r] * bw[1].y);
            float gg = tanhf_fast(fold[2][r] + bw[2].x + xr[r] * bw[2].y);
            float go = sigf(fold[3][r] + bw[3].x + xr[r] * bw[3].y);
            float cn = gf * c[r] + gi * gg;
            c[r] = cn;
            hnew[r] = go * tanhf_fast(cn);
        }

        // swizzled h-write: row = xbase+r, block (wr_mu - 2row)&31, offset wr_e
#pragma unroll
        for (int r = 0; r < 4; ++r)
            h_lds[1 - p][xbase + r][HSWZ(wr_mu, xbase + r) * 8 + wr_e] =
                (half_t)hnew[r];

        // projection of h_{t-1} (buf[p]; row w uniform -> constant block shift)
        {
            int pm = HSWZ(lane >> 1, w) * 8 + 4 * (lane & 1);
            f16x4 hv = *reinterpret_cast<const f16x4*>(&h_lds[p][w][pm]);
            f32x4 wv = *reinterpret_cast<const f32x4*>(&wl_lds[lane * 4]);
            float s = (float)hv[0] * wv[0] + (float)hv[1] * wv[1] +
                      (float)hv[2] * wv[2] + (float)hv[3] * wv[3];
#pragma unroll
            for (int m2 = 32; m2 >= 1; m2 >>= 1) s += __shfl_xor(s, m2, 64);
            float val = s + blin;
            ov = (((t - 1) & 63) == lane) ? val : ov;
            if ((t & 63) == 0 && t > 0)
                out[(size_t)(brow0 + w) * TN + (t - 64) + lane] = ov;
        }

        __syncthreads();  // h_t visible (proven barrier)
    }

    // epilogue: out[511] from final h (buf[0]) + flush block 448..511
    {
        int pm = HSWZ(lane >> 1, w) * 8 + 4 * (lane & 1);
        f16x4 hv = *reinterpret_cast<const f16x4*>(&h_lds[0][w][pm]);
        f32x4 wv = *reinterpret_cast<const f32x4*>(&wl_lds[lane * 4]);
        float s = (float)hv[0] * wv[0] + (float)hv[1] * wv[1] +
                  (float)hv[2] * wv[2] + (float)hv[3] * wv[3];
#pragma unroll
        for (int m2 = 32; m2 >= 1; m2 >>= 1) s += __shfl_xor(s, m2, 64);
        float val = s + blin;
        ov = (lane == 63) ? val : ov;
        out[(size_t)(brow0 + w) * TN + 448 + lane] = ov;
    }
}

extern "C" void kernel_launch(void* const* d_in, const int* in_sizes, int n_in,
                              void* d_out, int out_size, void* d_ws, size_t ws_size,
                              hipStream_t stream) {
    const float* x     = (const float*)d_in[0];
    const float* W_ih  = (const float*)d_in[1];
    const float* W_hh  = (const float*)d_in[2];
    const float* b_ih  = (const float*)d_in[3];
    const float* b_hh  = (const float*)d_in[4];
    const float* W_lin = (const float*)d_in[5];
    const float* b_lin = (const float*)d_in[6];
    float* out = (float*)d_out;

    const size_t packBytes = (size_t)4 * HN * HN * sizeof(half_t);  // 512 KB
    if (ws_size >= packBytes) {
        half_t* W4 = (half_t*)d_ws;
        pack_w<<<(4 * HN * HN + 255) / 256, 256, 0, stream>>>(W_hh, W4);
        lstm_hot<true><<<NBLK, THREADS, 0, stream>>>(
            x, W_ih, W4, W_hh, b_ih, b_hh, W_lin, b_lin, out);
    } else {
        lstm_hot<false><<<NBLK, THREADS, 0, stream>>>(
            x, W_ih, nullptr, W_hh, b_ih, b_hh, W_lin, b_lin, out);
    }
}

// Round 17
// 1174.326 us; speedup vs baseline: 1.4093x; 1.4093x over previous
//
#include <hip/hip_runtime.h>
#include <cmath>

#define BN 2048
#define TN 512
#define HN 256
#define ROWS 8
#define WAVES 8
#define THREADS 512
#define NBLK (BN / ROWS)   // 256 blocks = 1 per CU
#define HP (HN + 8)        // padded h row: 528 B

typedef _Float16 half_t;
typedef _Float16 f16x8 __attribute__((ext_vector_type(8)));
typedef _Float16 f16x4 __attribute__((ext_vector_type(4)));
typedef float f32x4 __attribute__((ext_vector_type(4)));
typedef unsigned uint2v __attribute__((ext_vector_type(2)));

__device__ __forceinline__ float sigf(float v) {
    return __builtin_amdgcn_rcpf(1.0f + __expf(-v));
}
__device__ __forceinline__ float tanhf_fast(float v) {
    return 1.0f - 2.0f * __builtin_amdgcn_rcpf(1.0f + __expf(2.0f * v));
}

// fold u0/u1 across lane halves (R15-proven builtin; shfl fallback)
__device__ __forceinline__ float fold_half(float a0, float a1, int lane) {
#if __has_builtin(__builtin_amdgcn_permlane32_swap)
    uint2v res = __builtin_amdgcn_permlane32_swap(
        __builtin_bit_cast(unsigned, a0), __builtin_bit_cast(unsigned, a1),
        false, false);
    return __builtin_bit_cast(float, res[0]);
#else
    float v0 = (lane < 32) ? a0 : 0.f;
    float sw = __shfl_xor(a1, 32, 64);
    return (lane >= 32) ? sw : v0;
#endif
}

// Pack W_hh [4H][H] fp32 -> fp16 fragment stream (UNSCALED — R5 numerics).
// idx bits: e[0:3) lane[3:9) kc[9:12) nt[12:15) w[15:18)
//   nt = u*4 + g; n = g*256 + 32*w + u*16 + (lane&15); k = kc*32+(lane>>4)*8+e
__global__ void pack_w(const float* __restrict__ Whh, half_t* __restrict__ W4) {
    int idx = blockIdx.x * 256 + threadIdx.x;
    if (idx >= 4 * HN * HN) return;
    int e = idx & 7;
    int lane = (idx >> 3) & 63;
    int kc = (idx >> 9) & 7;
    int nt = (idx >> 12) & 7;
    int w = (idx >> 15) & 7;
    int g = nt & 3, u = nt >> 2;
    int n = g * HN + 32 * w + u * 16 + (lane & 15);
    int k = kc * 32 + (lane >> 4) * 8 + e;
    W4[idx] = (half_t)Whh[(size_t)n * HN + k];
}

__device__ __forceinline__ f16x8 raw_frag(const float* __restrict__ Whh, int w,
                                          int g, int u, int kc, int li, int lh) {
    int n = g * HN + 32 * w + u * 16 + li;
    const float* p = Whh + (size_t)n * HN + kc * 32 + lh * 8;
    float4 lo = *reinterpret_cast<const float4*>(p);
    float4 hi = *reinterpret_cast<const float4*>(p + 4);
    f16x8 v;
    v[0] = (half_t)lo.x; v[1] = (half_t)lo.y;
    v[2] = (half_t)lo.z; v[3] = (half_t)lo.w;
    v[4] = (half_t)hi.x; v[5] = (half_t)hi.y;
    v[6] = (half_t)hi.z; v[7] = (half_t)hi.w;
    return v;
}

template <bool PACKED>
__global__ __launch_bounds__(THREADS, 2) void lstm_hot(
    const float* __restrict__ x,      // [B][T]
    const float* __restrict__ W_ih,   // [4H]
    const half_t* __restrict__ W4,    // packed fragments (PACKED)
    const float* __restrict__ Whh,    // raw fallback
    const float* __restrict__ b_ih, const float* __restrict__ b_hh,
    const float* __restrict__ W_lin, const float* __restrict__ b_lin,
    float* __restrict__ out)          // [B][T]
{
    __shared__ __align__(16) half_t ldsW[WAVES][2][8][512];  // 128 KB (gate-3)
    __shared__ __align__(16) half_t h_lds[2][16][HP];        // 16.5 KB dbuf
    __shared__ float2 bw_lds[4 * HN];                        // 8 KB {bias, w_ih}
    __shared__ float wl_lds[HN];                             // 1 KB

    const int tid = threadIdx.x;
    const int lane = tid & 63;
    const int w = tid >> 6;        // wave w: units 32w..32w+31, out row w
    const int li = lane & 15;
    const int lh = lane >> 4;      // 0..3
    const int brow0 = blockIdx.x * ROWS;

    for (int i = tid; i < 4 * HN; i += THREADS)
        bw_lds[i] = make_float2(b_ih[i] + b_hh[i], W_ih[i]);
    for (int i = tid; i < HN; i += THREADS) wl_lds[i] = W_lin[i];
    for (int i = tid; i < 2 * 16 * HP; i += THREADS)
        (&h_lds[0][0][0])[i] = (half_t)0.0f;

    // ---- weights: gates 0..2 in registers/AGPRs (192), gate 3 in LDS ----
    f16x8 Wv[3][2][8];
    if (PACKED) {
        const half_t* Wb = W4 + ((size_t)w << 15) + lane * 8;
#pragma unroll
        for (int g = 0; g < 3; ++g)
#pragma unroll
            for (int u = 0; u < 2; ++u)
#pragma unroll
                for (int kc = 0; kc < 8; ++kc)
                    Wv[g][u][kc] = *reinterpret_cast<const f16x8*>(
                        Wb + (((u * 4 + g) << 12) | (kc << 9)));
#pragma unroll
        for (int u = 0; u < 2; ++u)
#pragma unroll
            for (int kc = 0; kc < 8; ++kc)
                *reinterpret_cast<f16x8*>(&ldsW[w][u][kc][lane * 8]) =
                    *reinterpret_cast<const f16x8*>(
                        Wb + (((u * 4 + 3) << 12) | (kc << 9)));
    } else {
#pragma unroll
        for (int g = 0; g < 3; ++g)
#pragma unroll
            for (int u = 0; u < 2; ++u)
#pragma unroll
                for (int kc = 0; kc < 8; ++kc)
                    Wv[g][u][kc] = raw_frag(Whh, w, g, u, kc, li, lh);
#pragma unroll
        for (int u = 0; u < 2; ++u)
#pragma unroll
            for (int kc = 0; kc < 8; ++kc)
                *reinterpret_cast<f16x8*>(&ldsW[w][u][kc][lane * 8]) =
                    raw_frag(Whh, w, 3, u, kc, li, lh);
    }

    const int unit = 32 * w + (lane >= 32 ? 16 : 0) + li;
    const int xbase = (lh & 1) * 4;  // rows xbase..xbase+3
    const float* xptr = x + (size_t)(brow0 + xbase) * TN;

    float c[4] = {0.0f, 0.0f, 0.0f, 0.0f};
    const float blin = b_lin[0];
    float ov = 0.0f;  // out[w][·]: lane s holds out value for step (blk*64+s)

    __syncthreads();

    // hoist loop-invariant bias/w_ih into registers (verified via R11 pass)
    float2 bw[4];
#pragma unroll
    for (int g = 0; g < 4; ++g) bw[g] = bw_lds[g * HN + unit];

    for (int t = 0; t < TN; ++t) {
        const int p = t & 1;  // buffer holding h_{t-1}

        // x for this step (issued early; L1-resident after first sweep)
        float xr[4];
#pragma unroll
        for (int r = 0; r < 4; ++r) xr[r] = xptr[(size_t)r * TN + t];

        // gates: 8 independent MFMA chains, A loaded once per kc
        f32x4 acc[4][2];
#pragma unroll
        for (int g = 0; g < 4; ++g)
#pragma unroll
            for (int u = 0; u < 2; ++u)
                acc[g][u] = f32x4{0.f, 0.f, 0.f, 0.f};

        __builtin_amdgcn_s_setprio(1);
#pragma unroll
        for (int kc = 0; kc < 8; ++kc) {
            f16x8 a = *reinterpret_cast<const f16x8*>(
                &h_lds[p][li][kc * 32 + lh * 8]);
            f16x8 b3u0 = *reinterpret_cast<const f16x8*>(&ldsW[w][0][kc][lane * 8]);
            f16x8 b3u1 = *reinterpret_cast<const f16x8*>(&ldsW[w][1][kc][lane * 8]);
#pragma unroll
            for (int g = 0; g < 3; ++g) {
                acc[g][0] = __builtin_amdgcn_mfma_f32_16x16x32_f16(
                    a, Wv[g][0][kc], acc[g][0], 0, 0, 0);
                acc[g][1] = __builtin_amdgcn_mfma_f32_16x16x32_f16(
                    a, Wv[g][1][kc], acc[g][1], 0, 0, 0);
            }
            acc[3][0] = __builtin_amdgcn_mfma_f32_16x16x32_f16(a, b3u0, acc[3][0], 0, 0, 0);
            acc[3][1] = __builtin_amdgcn_mfma_f32_16x16x32_f16(a, b3u1, acc[3][1], 0, 0, 0);
        }
        __builtin_amdgcn_s_setprio(0);

        // fold u0/u1 across lane halves (builtin permlane32_swap; shfl fallback)
        float fold[4][4];
#pragma unroll
        for (int g = 0; g < 4; ++g)
#pragma unroll
            for (int r = 0; r < 4; ++r)
                fold[g][r] = fold_half(acc[g][0][r], acc[g][1][r], lane);

        float hnew[4];
#pragma unroll
        for (int r = 0; r < 4; ++r) {
            float gi = sigf(fold[0][r] + bw[0].x + xr[r] * bw[0].y);
            float gf = sigf(fold[1][r] + bw[1].x + xr[r] * bw[1].y);
            float gg = tanhf_fast(fold[2][r] + bw[2].x + xr[r] * bw[2].y);
            float go = sigf(fold[3][r] + bw[3].x + xr[r] * bw[3].y);
            float cn = gf * c[r] + gi * gg;
            c[r] = cn;
            hnew[r] = go * tanhf_fast(cn);
        }

#pragma unroll
        for (int r = 0; r < 4; ++r)
            h_lds[1 - p][xbase + r][unit] = (half_t)hnew[r];

        // projection of h_{t-1} (buf[p] valid until step t+1's write),
        // sunk after h-write to overlap the barrier wait (R12-proven).
        {
            f16x4 hv = *reinterpret_cast<const f16x4*>(&h_lds[p][w][lane * 4]);
            f32x4 wv = *reinterpret_cast<const f32x4*>(&wl_lds[lane * 4]);
            float s = (float)hv[0] * wv[0] + (float)hv[1] * wv[1] +
                      (float)hv[2] * wv[2] + (float)hv[3] * wv[3];
#pragma unroll
            for (int m2 = 32; m2 >= 1; m2 >>= 1) s += __shfl_xor(s, m2, 64);
            float val = s + blin;
            ov = (((t - 1) & 63) == lane) ? val : ov;
            if ((t & 63) == 0 && t > 0)
                out[(size_t)(brow0 + w) * TN + (t - 64) + lane] = ov;
        }

        __syncthreads();  // h_t visible (proven barrier)
    }

    // epilogue: out[511] from final h (buf[0]) + flush block 448..511
    {
        f16x4 hv = *reinterpret_cast<const f16x4*>(&h_lds[0][w][lane * 4]);
        f32x4 wv = *reinterpret_cast<const f32x4*>(&wl_lds[lane * 4]);
        float s = (float)hv[0] * wv[0] + (float)hv[1] * wv[1] +
                  (float)hv[2] * wv[2] + (float)hv[3] * wv[3];
#pragma unroll
        for (int m2 = 32; m2 >= 1; m2 >>= 1) s += __shfl_xor(s, m2, 64);
        float val = s + blin;
        ov = (lane == 63) ? val : ov;
        out[(size_t)(brow0 + w) * TN + 448 + lane] = ov;
    }
}

extern "C" void kernel_launch(void* const* d_in, const int* in_sizes, int n_in,
                              void* d_out, int out_size, void* d_ws, size_t ws_size,
                              hipStream_t stream) {
    const float* x     = (const float*)d_in[0];
    const float* W_ih  = (const float*)d_in[1];
    const float* W_hh  = (const float*)d_in[2];
    const float* b_ih  = (const float*)d_in[3];
    const float* b_hh  = (const float*)d_in[4];
    const float* W_lin = (const float*)d_in[5];
    const float* b_lin = (const float*)d_in[6];
    float* out = (float*)d_out;

    const size_t packBytes = (size_t)4 * HN * HN * sizeof(half_t);  // 512 KB
    if (ws_size >= packBytes) {
        half_t* W4 = (half_t*)d_ws;
        pack_w<<<(4 * HN * HN + 255) / 256, 256, 0, stream>>>(W_hh, W4);
        lstm_hot<true><<<NBLK, THREADS, 0, stream>>>(
            x, W_ih, W4, W_hh, b_ih, b_hh, W_lin, b_lin, out);
    } else {
        lstm_hot<false><<<NBLK, THREADS, 0, stream>>>(
            x, W_ih, nullptr, W_hh, b_ih, b_hh, W_lin, b_lin, out);
    }
}